// Round 1
// baseline (19781.001 us; speedup 1.0000x reference)
//
#include <hip/hip_runtime.h>
#include <hip/hip_bf16.h>
#include <math.h>

#define BQ 64
#define TENC_ 512
#define TDEC_ 64
#define HH 1024
#define VV 1024
#define AA 512

// out[m,n] (+)= sum_k X[m*ldx+k] * W[n*ldw+koff+k] (+ bias[n])
// grid: (N/64, M/64), block (16,16). All dims divisible by 64/16 in this problem.
template<bool ACCUM, bool BIAS, bool REMAP>
__global__ __launch_bounds__(256)
void gemm_xwt(const float* __restrict__ X, int ldx,
              const float* __restrict__ W, int ldw, int koff,
              const float* __restrict__ bias,
              float* __restrict__ out, int ldo, int K) {
    __shared__ float Xs[16][68];
    __shared__ float Ws[16][68];
    const int tx = threadIdx.x, ty = threadIdx.y;
    const int tid = ty * 16 + tx;
    const int mBase = blockIdx.y * 64;
    const int nBase = blockIdx.x * 64;
    const int lrow = tid >> 2;        // 0..63
    const int lk = (tid & 3) << 2;    // 0,4,8,12
    float acc[4][4] = {};
    for (int kk = 0; kk < K; kk += 16) {
        const float4 xv = *(const float4*)(X + (size_t)(mBase + lrow) * ldx + kk + lk);
        const float4 wv = *(const float4*)(W + (size_t)(nBase + lrow) * ldw + koff + kk + lk);
        __syncthreads();
        Xs[lk + 0][lrow] = xv.x; Xs[lk + 1][lrow] = xv.y;
        Xs[lk + 2][lrow] = xv.z; Xs[lk + 3][lrow] = xv.w;
        Ws[lk + 0][lrow] = wv.x; Ws[lk + 1][lrow] = wv.y;
        Ws[lk + 2][lrow] = wv.z; Ws[lk + 3][lrow] = wv.w;
        __syncthreads();
        #pragma unroll
        for (int k = 0; k < 16; ++k) {
            float a0 = Xs[k][ty * 4 + 0], a1 = Xs[k][ty * 4 + 1];
            float a2 = Xs[k][ty * 4 + 2], a3 = Xs[k][ty * 4 + 3];
            float b0 = Ws[k][tx * 4 + 0], b1 = Ws[k][tx * 4 + 1];
            float b2 = Ws[k][tx * 4 + 2], b3 = Ws[k][tx * 4 + 3];
            acc[0][0] += a0 * b0; acc[0][1] += a0 * b1; acc[0][2] += a0 * b2; acc[0][3] += a0 * b3;
            acc[1][0] += a1 * b0; acc[1][1] += a1 * b1; acc[1][2] += a1 * b2; acc[1][3] += a1 * b3;
            acc[2][0] += a2 * b0; acc[2][1] += a2 * b1; acc[2][2] += a2 * b2; acc[2][3] += a2 * b3;
            acc[3][0] += a3 * b0; acc[3][1] += a3 * b1; acc[3][2] += a3 * b2; acc[3][3] += a3 * b3;
        }
    }
    #pragma unroll
    for (int i = 0; i < 4; ++i) {
        const int m = mBase + ty * 4 + i;
        #pragma unroll
        for (int j = 0; j < 4; ++j) {
            const int n = nBase + tx * 4 + j;
            size_t oidx;
            if (REMAP) {
                // m = t*64 + b  ->  out row = b*TDEC + t
                const int b = m & 63, t = m >> 6;
                oidx = (size_t)(b * TDEC_ + t) * ldo + n;
            } else {
                oidx = (size_t)m * ldo + n;
            }
            float v = acc[i][j];
            if (BIAS) v += bias[n];
            if (ACCUM) v += out[oidx];
            out[oidx] = v;
        }
    }
}

__global__ void embed_kernel(const int* __restrict__ target, const float* __restrict__ table,
                             float* __restrict__ embs) {
    const int bid = blockIdx.x;           // = t*64 + b
    const int t = bid >> 6, b = bid & 63;
    const int tok = (t == 0) ? 0 : target[b * TDEC_ + t - 1];
    const float* src = table + (size_t)tok * AA;
    float* dst = embs + (size_t)bid * AA;
    for (int a = threadIdx.x; a < AA; a += 256) dst[a] = src[a];
}

__global__ void lstm_cell(const float* __restrict__ gates, float* __restrict__ c,
                          float* __restrict__ h, float* __restrict__ hAll) {
    const int idx = blockIdx.x * 256 + threadIdx.x;   // b*H + hh
    const int b = idx >> 10, hh = idx & 1023;
    const float* g = gates + (size_t)b * 4 * HH;
    const float gi = g[hh], gf = g[HH + hh], gg = g[2 * HH + hh], go = g[3 * HH + hh];
    const float ii = 1.f / (1.f + expf(-gi));
    const float ff = 1.f / (1.f + expf(-gf));
    const float oo = 1.f / (1.f + expf(-go));
    const float c2 = ff * c[idx] + ii * tanhf(gg);
    const float hv = oo * tanhf(c2);
    c[idx] = c2;
    h[idx] = hv;
    if (hAll) hAll[idx] = hv;
}

__global__ void attn_scores(const float* __restrict__ Kbuf, const float* __restrict__ q,
                            float* __restrict__ scores) {
    const int b = blockIdx.x;
    const int wave = threadIdx.x >> 6, lane = threadIdx.x & 63;
    const int t = blockIdx.y * 4 + wave;
    __shared__ float qs[AA];
    for (int a = threadIdx.x; a < AA; a += 256) qs[a] = q[b * AA + a];
    __syncthreads();
    const float* kr = Kbuf + ((size_t)b * TENC_ + t) * AA + lane * 8;
    const float4 k1 = *(const float4*)kr;
    const float4 k2 = *(const float4*)(kr + 4);
    const int a0 = lane * 8;
    float s = k1.x * qs[a0] + k1.y * qs[a0 + 1] + k1.z * qs[a0 + 2] + k1.w * qs[a0 + 3]
            + k2.x * qs[a0 + 4] + k2.y * qs[a0 + 5] + k2.z * qs[a0 + 6] + k2.w * qs[a0 + 7];
    for (int off = 32; off; off >>= 1) s += __shfl_xor(s, off);
    if (lane == 0) scores[(size_t)b * TENC_ + t] = s;
}

__global__ void softmax_rows(float* __restrict__ scores) {
    const int b = blockIdx.x;
    float* s = scores + (size_t)b * TENC_;
    __shared__ float red[256];
    const int tid = threadIdx.x;
    const float v0 = s[tid], v1 = s[tid + 256];
    red[tid] = fmaxf(v0, v1);
    __syncthreads();
    for (int off = 128; off; off >>= 1) {
        if (tid < off) red[tid] = fmaxf(red[tid], red[tid + off]);
        __syncthreads();
    }
    const float m = red[0];
    __syncthreads();
    const float e0 = expf(v0 - m), e1 = expf(v1 - m);
    red[tid] = e0 + e1;
    __syncthreads();
    for (int off = 128; off; off >>= 1) {
        if (tid < off) red[tid] += red[tid + off];
        __syncthreads();
    }
    const float inv = 1.f / red[0];
    s[tid] = e0 * inv;
    s[tid + 256] = e1 * inv;
}

__global__ void attn_out(const float* __restrict__ scores, const float* __restrict__ Vbuf,
                         float* __restrict__ attn) {
    const int b = blockIdx.x;
    const int a = blockIdx.y * 256 + threadIdx.x;
    __shared__ float wsm[TENC_];
    for (int t = threadIdx.x; t < TENC_; t += 256) wsm[t] = scores[(size_t)b * TENC_ + t];
    __syncthreads();
    const float* vb = Vbuf + (size_t)b * TENC_ * AA + a;
    float acc = 0.f;
    for (int t = 0; t < TENC_; ++t) acc += wsm[t] * vb[(size_t)t * AA];
    attn[b * AA + a] = acc;
}

__global__ void ln_relu(float* __restrict__ x, const float* __restrict__ g,
                        const float* __restrict__ bb) {
    const int row = blockIdx.x;
    float* xr = x + (size_t)row * 2 * VV;
    const int tid = threadIdx.x;
    __shared__ float red[256];
    float lv[8];
    float s = 0.f;
    #pragma unroll
    for (int i = 0; i < 8; ++i) { lv[i] = xr[tid + i * 256]; s += lv[i]; }
    red[tid] = s;
    __syncthreads();
    for (int off = 128; off; off >>= 1) {
        if (tid < off) red[tid] += red[tid + off];
        __syncthreads();
    }
    const float mu = red[0] * (1.f / 2048.f);
    __syncthreads();
    s = 0.f;
    #pragma unroll
    for (int i = 0; i < 8; ++i) { const float d = lv[i] - mu; s += d * d; }
    red[tid] = s;
    __syncthreads();
    for (int off = 128; off; off >>= 1) {
        if (tid < off) red[tid] += red[tid + off];
        __syncthreads();
    }
    const float inv = rsqrtf(red[0] * (1.f / 2048.f) + 1e-5f);
    #pragma unroll
    for (int i = 0; i < 8; ++i) {
        const int n = tid + i * 256;
        const float v = (lv[i] - mu) * inv * g[n] + bb[n];
        xr[n] = fmaxf(v, 0.f);
    }
}

__global__ void ce_loss(const float* __restrict__ logits, const int* __restrict__ target,
                        float* __restrict__ acc) {
    const int r = blockIdx.x;   // = b*TDEC + t, matches both d_out rows and target layout
    const float* row = logits + (size_t)r * VV;
    const int tid = threadIdx.x;
    __shared__ float red[256];
    float lv[4];
    float m = -1e30f;
    #pragma unroll
    for (int i = 0; i < 4; ++i) { lv[i] = row[tid + i * 256]; m = fmaxf(m, lv[i]); }
    red[tid] = m;
    __syncthreads();
    for (int off = 128; off; off >>= 1) {
        if (tid < off) red[tid] = fmaxf(red[tid], red[tid + off]);
        __syncthreads();
    }
    m = red[0];
    __syncthreads();
    float s = 0.f;
    #pragma unroll
    for (int i = 0; i < 4; ++i) s += expf(lv[i] - m);
    red[tid] = s;
    __syncthreads();
    for (int off = 128; off; off >>= 1) {
        if (tid < off) red[tid] += red[tid + off];
        __syncthreads();
    }
    if (tid == 0) {
        const float nll = logf(red[0]) + m - row[target[r]];
        atomicAdd(acc, nll);
    }
}

__global__ void finalize_loss(const float* __restrict__ acc, float* __restrict__ out) {
    out[0] = acc[0] * (1.f / 4096.f);
}

extern "C" void kernel_launch(void* const* d_in, const int* in_sizes, int n_in,
                              void* d_out, int out_size, void* d_ws, size_t ws_size,
                              hipStream_t stream) {
    const float* enc       = (const float*)d_in[0];
    const int*   target    = (const int*)d_in[1];
    const float* emb_table = (const float*)d_in[2];
    const float* att_wq    = (const float*)d_in[3];
    const float* att_bq    = (const float*)d_in[4];
    const float* att_wk    = (const float*)d_in[5];
    const float* att_bk    = (const float*)d_in[6];
    const float* att_wv    = (const float*)d_in[7];
    const float* att_bv    = (const float*)d_in[8];
    const float* w_ih0     = (const float*)d_in[9];
    const float* w_hh0     = (const float*)d_in[10];
    const float* b_ih0     = (const float*)d_in[11];
    const float* b_hh0     = (const float*)d_in[12];
    const float* w_ih1     = (const float*)d_in[13];
    const float* w_hh1     = (const float*)d_in[14];
    const float* b_ih1     = (const float*)d_in[15];
    const float* b_hh1     = (const float*)d_in[16];
    const float* mlp_w1    = (const float*)d_in[17];
    const float* mlp_b1    = (const float*)d_in[18];
    const float* ln_g      = (const float*)d_in[19];
    const float* ln_b      = (const float*)d_in[20];
    const float* mlp_w2    = (const float*)d_in[21];
    const float* mlp_b2    = (const float*)d_in[22];
    float* out = (float*)d_out;
    float* ws  = (float*)d_ws;

    size_t oK    = 0;
    size_t oV    = oK + (size_t)BQ * TENC_ * AA;
    size_t oE    = oV + (size_t)BQ * TENC_ * AA;
    size_t oH0   = oE + (size_t)TDEC_ * BQ * AA;
    size_t oC0   = oH0 + (size_t)BQ * HH;
    size_t oH1   = oC0 + (size_t)BQ * HH;
    size_t oC1   = oH1 + (size_t)BQ * HH;
    size_t oAttn = oC1 + (size_t)BQ * HH;
    size_t oGates= oAttn + (size_t)BQ * AA;
    size_t oQ    = oGates + (size_t)BQ * 4 * HH;
    size_t oS    = oQ + (size_t)BQ * AA;
    size_t oH1A  = oS + (size_t)BQ * TENC_;
    size_t oX1   = oH1A + (size_t)TDEC_ * BQ * HH;
    size_t oAcc  = oX1 + (size_t)TDEC_ * BQ * 2 * VV;

    float *Kb = ws + oK, *Vb = ws + oV, *Eb = ws + oE;
    float *h0 = ws + oH0, *c0 = ws + oC0, *h1 = ws + oH1, *c1 = ws + oC1;
    float *attn = ws + oAttn, *gates = ws + oGates, *qb = ws + oQ, *sc = ws + oS;
    float *h1a = ws + oH1A, *x1 = ws + oX1, *acc = ws + oAcc;

    // zero the recurrent state (h0,c0,h1,c1,attn are contiguous) and the loss accumulator
    hipMemsetAsync(h0, 0, (size_t)(4 * BQ * HH + BQ * AA) * sizeof(float), stream);
    hipMemsetAsync(acc, 0, sizeof(float), stream);

    dim3 blk(16, 16);

    // K = enc @ wk.T + bk ; V = enc @ wv.T + bv     [B*TENC, A], K-dim H
    gemm_xwt<false, true, false><<<dim3(AA / 64, BQ * TENC_ / 64), blk, 0, stream>>>(
        enc, HH, att_wk, HH, 0, att_bk, Kb, AA, HH);
    gemm_xwt<false, true, false><<<dim3(AA / 64, BQ * TENC_ / 64), blk, 0, stream>>>(
        enc, HH, att_wv, HH, 0, att_bv, Vb, AA, HH);
    embed_kernel<<<TDEC_ * BQ, 256, 0, stream>>>(target, emb_table, Eb);

    for (int t = 0; t < TDEC_; ++t) {
        const float* et = Eb + (size_t)t * BQ * AA;
        // gates0 = e @ wih0[:, :A].T + bih0  +  attn @ wih0[:, A:].T + bhh0  +  h0 @ whh0.T
        gemm_xwt<false, true, false><<<dim3(4 * HH / 64, 1), blk, 0, stream>>>(
            et, AA, w_ih0, HH, 0, b_ih0, gates, 4 * HH, AA);
        gemm_xwt<true, true, false><<<dim3(4 * HH / 64, 1), blk, 0, stream>>>(
            attn, AA, w_ih0, HH, AA, b_hh0, gates, 4 * HH, AA);
        gemm_xwt<true, false, false><<<dim3(4 * HH / 64, 1), blk, 0, stream>>>(
            h0, HH, w_hh0, HH, 0, nullptr, gates, 4 * HH, HH);
        lstm_cell<<<BQ * HH / 256, 256, 0, stream>>>(gates, c0, h0, nullptr);
        // gates1 = h0n @ wih1.T + bih1  +  h1 @ whh1.T + bhh1
        gemm_xwt<false, true, false><<<dim3(4 * HH / 64, 1), blk, 0, stream>>>(
            h0, HH, w_ih1, HH, 0, b_ih1, gates, 4 * HH, HH);
        gemm_xwt<true, true, false><<<dim3(4 * HH / 64, 1), blk, 0, stream>>>(
            h1, HH, w_hh1, HH, 0, b_hh1, gates, 4 * HH, HH);
        lstm_cell<<<BQ * HH / 256, 256, 0, stream>>>(gates, c1, h1, h1a + (size_t)t * BQ * HH);
        // attention
        gemm_xwt<false, true, false><<<dim3(AA / 64, 1), blk, 0, stream>>>(
            h1, HH, att_wq, HH, 0, att_bq, qb, AA, HH);
        attn_scores<<<dim3(BQ, TENC_ / 4), 256, 0, stream>>>(Kb, qb, sc);
        softmax_rows<<<BQ, 256, 0, stream>>>(sc);
        attn_out<<<dim3(BQ, 2), 256, 0, stream>>>(sc, Vb, attn);
    }

    // batched MLP head over all (t,b) rows
    gemm_xwt<false, true, false><<<dim3(2 * VV / 64, TDEC_ * BQ / 64), blk, 0, stream>>>(
        h1a, HH, mlp_w1, HH, 0, mlp_b1, x1, 2 * VV, HH);
    ln_relu<<<TDEC_ * BQ, 256, 0, stream>>>(x1, ln_g, ln_b);
    gemm_xwt<false, true, true><<<dim3(VV / 64, TDEC_ * BQ / 64), blk, 0, stream>>>(
        x1, 2 * VV, mlp_w2, 2 * VV, 0, mlp_b2, out, VV, 2 * VV);

    ce_loss<<<BQ * TDEC_, 256, 0, stream>>>(out, target, acc);
    finalize_loss<<<1, 1, 0, stream>>>(acc, out + (size_t)BQ * TDEC_ * VV);
}

// Round 3
// 4797.886 us; speedup vs baseline: 4.1229x; 4.1229x over previous
//
#include <hip/hip_runtime.h>
#include <hip/hip_bf16.h>
#include <math.h>

#define BQ 64
#define TENC_ 512
#define TDEC_ 64
#define HH 1024
#define VV 1024
#define AA 512

typedef short v8s __attribute__((ext_vector_type(8)));
typedef float v4f __attribute__((ext_vector_type(4)));
typedef unsigned short u16;

__device__ __forceinline__ u16 f2bf(float f) {
    unsigned u = __builtin_bit_cast(unsigned, f);
    u = u + 0x7FFFu + ((u >> 16) & 1u);
    return (u16)(u >> 16);
}
__device__ __forceinline__ float bf2f(u16 h) {
    unsigned u = ((unsigned)h) << 16;
    return __builtin_bit_cast(float, u);
}
__device__ __forceinline__ uint4 pack8(const float4 a, const float4 b) {
    uint4 o;
    o.x = (unsigned)f2bf(a.x) | ((unsigned)f2bf(a.y) << 16);
    o.y = (unsigned)f2bf(a.z) | ((unsigned)f2bf(a.w) << 16);
    o.z = (unsigned)f2bf(b.x) | ((unsigned)f2bf(b.y) << 16);
    o.w = (unsigned)f2bf(b.z) | ((unsigned)f2bf(b.w) << 16);
    return o;
}

// ---------------- conversion / layout kernels ----------------

__global__ void conv_f2b(const float* __restrict__ src, u16* __restrict__ dst, int n8) {
    int i = blockIdx.x * 256 + threadIdx.x;
    if (i >= n8) return;
    const float4 a = *(const float4*)(src + (size_t)i * 8);
    const float4 b = *(const float4*)(src + (size_t)i * 8 + 4);
    ((uint4*)dst)[i] = pack8(a, b);
}

// wcat[n][0:1024] = wih[n][:], wcat[n][1024:2048] = whh[n][:]  (bf16)
__global__ void build_wcat(const float* __restrict__ wih, const float* __restrict__ whh,
                           u16* __restrict__ wcat) {
    int i = blockIdx.x * 256 + threadIdx.x;   // chunk of 8 elems, total 4096*2048/8
    if (i >= 4096 * 2048 / 8) return;
    int row = i >> 8, k = (i & 255) * 8;
    const float* s = (k < 1024) ? (wih + (size_t)row * 1024 + k)
                                : (whh + (size_t)row * 1024 + (k - 1024));
    ((uint4*)wcat)[i] = pack8(*(const float4*)s, *(const float4*)(s + 4));
}

// Eb[t][b][a] bf16 = emb_table[prev_token(t,b)][a]
__global__ void embed_k(const int* __restrict__ tgt, const float* __restrict__ table,
                        u16* __restrict__ Eb) {
    int bid = blockIdx.x;            // t*64 + b
    int t = bid >> 6, b = bid & 63;
    int tok = (t == 0) ? 0 : tgt[b * TDEC_ + t - 1];
    int lane = threadIdx.x;          // 64 threads, 8 elems each
    const float* src = table + (size_t)tok * AA + lane * 8;
    ((uint4*)Eb)[(size_t)bid * 64 + lane] = pack8(*(const float4*)src, *(const float4*)(src + 4));
}

// ---------------- per-step MFMA GEMM (M=64, K-chunked by blockIdx.y) ----------------
// gp[(kc*64 + m)*N + n] = sum_{k in chunk kc} A_kc[m][k] * W[n][kc*512 + k]
__global__ __launch_bounds__(256) void gemm_step(
    const u16* A0, const u16* A1, const u16* A2, const u16* A3,
    int l0, int l1, int l2, int l3,
    const u16* __restrict__ W, int ldw,
    float* __restrict__ gp, int N) {
    __shared__ u16 As[64 * 512];
    const int tid = threadIdx.x;
    const int kc = blockIdx.y;
    const u16* A = (kc == 0) ? A0 : (kc == 1) ? A1 : (kc == 2) ? A2 : A3;
    const int lda = (kc == 0) ? l0 : (kc == 1) ? l1 : (kc == 2) ? l2 : l3;
    // stage A chunk [64][512] bf16 into LDS with XOR swizzle
    for (int it = 0; it < 16; ++it) {
        int flat = it * 256 + tid;
        int row = flat >> 6, c8 = flat & 63;
        uint4 v = *(const uint4*)(A + (size_t)row * lda + c8 * 8);
        int byte = (row * 1024 + c8 * 16) ^ ((row & 7) << 4);
        *(uint4*)((char*)As + byte) = v;
    }
    __syncthreads();
    const int w = tid >> 6, lane = tid & 63;
    const int li = lane & 15, lg = lane >> 4;
    const u16* Wp = W + (size_t)(blockIdx.x * 64 + w * 16 + li) * ldw + kc * 512 + lg * 8;
    v4f acc[4];
    #pragma unroll
    for (int mt = 0; mt < 4; ++mt) acc[mt] = (v4f){0.f, 0.f, 0.f, 0.f};
    for (int ks = 0; ks < 16; ++ks) {
        v8s wf = *(const v8s*)(Wp + ks * 32);
        #pragma unroll
        for (int mt = 0; mt < 4; ++mt) {
            int row = mt * 16 + li;
            int byte = (row * 1024 + ks * 64 + lg * 16) ^ ((row & 7) << 4);
            v8s af = *(const v8s*)((char*)As + byte);
            acc[mt] = __builtin_amdgcn_mfma_f32_16x16x32_bf16(af, wf, acc[mt], 0, 0, 0);
        }
    }
    const int col = blockIdx.x * 64 + w * 16 + li;
    float* g = gp + (size_t)kc * 64 * N;
    #pragma unroll
    for (int mt = 0; mt < 4; ++mt) {
        #pragma unroll
        for (int r = 0; r < 4; ++r) {
            int b = mt * 16 + lg * 4 + r;
            g[(size_t)b * N + col] = acc[mt][r];
        }
    }
}

// ---------------- LSTM cell (sums 4 K-partials + biases) ----------------
__global__ void cell_k(const float* __restrict__ gp, const float* __restrict__ bih,
                       const float* __restrict__ bhh, float* __restrict__ c,
                       u16* __restrict__ h, u16* __restrict__ hAll) {
    int idx = blockIdx.x * 256 + threadIdx.x;   // 64*1024 total
    int hh = idx & 1023, b = idx >> 10;
    float g4[4];
    #pragma unroll
    for (int g = 0; g < 4; ++g) {
        int col = g * 1024 + hh;
        float s = bih[col] + bhh[col];
        #pragma unroll
        for (int kc = 0; kc < 4; ++kc) s += gp[((size_t)(kc * 64 + b)) * 4096 + col];
        g4[g] = s;
    }
    float ii = 1.f / (1.f + expf(-g4[0]));
    float ff = 1.f / (1.f + expf(-g4[1]));
    float oo = 1.f / (1.f + expf(-g4[3]));
    float c2 = ff * c[idx] + ii * tanhf(g4[2]);
    float hv = oo * tanhf(c2);
    c[idx] = c2;
    h[idx] = f2bf(hv);
    if (hAll) hAll[idx] = f2bf(hv);
}

// ---------------- attention ----------------

// sraw[b][t] = dot(Kb[b,t,:], q[b,:]),  q = qp0 + qp1 + bq
__global__ __launch_bounds__(256) void scores_k(
    const u16* __restrict__ Kb, const float* __restrict__ qp,
    const float* __restrict__ bq, float* __restrict__ sraw) {
    __shared__ float qs[AA];
    int b = blockIdx.x, tc = blockIdx.y, tid = threadIdx.x;
    for (int a = tid; a < AA; a += 256)
        qs[a] = qp[(size_t)b * AA + a] + qp[(size_t)(64 + b) * AA + a] + bq[a];
    __syncthreads();
    int w = tid >> 6, lane = tid & 63, lg = lane >> 4, li = lane & 15;
    for (int sub = 0; sub < 4; ++sub) {
        int t = tc * 64 + w * 16 + sub * 4 + lg;
        const u16* kr = Kb + ((size_t)b * TENC_ + t) * AA + li * 32;
        float s = 0.f;
        #pragma unroll
        for (int j = 0; j < 4; ++j) {
            uint4 v = *(const uint4*)(kr + j * 8);
            const u16* pv = (const u16*)&v;
            #pragma unroll
            for (int e = 0; e < 8; ++e) s += bf2f(pv[e]) * qs[li * 32 + j * 8 + e];
        }
        s += __shfl_xor(s, 1); s += __shfl_xor(s, 2);
        s += __shfl_xor(s, 4); s += __shfl_xor(s, 8);
        if (li == 0) sraw[(size_t)b * TENC_ + t] = s;
    }
}

// softmax(sraw[b]) then attnb[b][a0:a0+128] = sum_t p[t]*V[b][t][:]
__global__ __launch_bounds__(256) void attnout_k(
    const float* __restrict__ sraw, const u16* __restrict__ Vb, u16* __restrict__ attnb) {
    __shared__ float red[256];
    __shared__ float p[TENC_];
    __shared__ float accs[4][128];
    int b = blockIdx.x, a0 = blockIdx.y * 128, tid = threadIdx.x;
    float s0 = sraw[(size_t)b * TENC_ + tid], s1 = sraw[(size_t)b * TENC_ + 256 + tid];
    red[tid] = fmaxf(s0, s1);
    __syncthreads();
    for (int off = 128; off; off >>= 1) {
        if (tid < off) red[tid] = fmaxf(red[tid], red[tid + off]);
        __syncthreads();
    }
    float m = red[0];
    __syncthreads();
    float e0 = expf(s0 - m), e1 = expf(s1 - m);
    red[tid] = e0 + e1;
    __syncthreads();
    for (int off = 128; off; off >>= 1) {
        if (tid < off) red[tid] += red[tid + off];
        __syncthreads();
    }
    float inv = 1.f / red[0];
    p[tid] = e0 * inv; p[tid + 256] = e1 * inv;
    __syncthreads();
    int w = tid >> 6, lane = tid & 63;
    float a0f = 0.f, a1f = 0.f;
    for (int t = w; t < TENC_; t += 4) {
        unsigned v = *(const unsigned*)(Vb + ((size_t)b * TENC_ + t) * AA + a0 + lane * 2);
        float pw = p[t];
        a0f += pw * bf2f((u16)(v & 0xFFFF));
        a1f += pw * bf2f((u16)(v >> 16));
    }
    accs[w][lane * 2] = a0f; accs[w][lane * 2 + 1] = a1f;
    __syncthreads();
    if (tid < 128) {
        float s = accs[0][tid] + accs[1][tid] + accs[2][tid] + accs[3][tid];
        attnb[(size_t)b * AA + a0 + tid] = f2bf(s);
    }
}

// ---------------- big MFMA GEMM: 128x128 tile ----------------
// OUT: 0 = f32+bias, 1 = bf16+bias, 2 = f32+bias with (t*64+b)->(b*64+t) row remap
template<int OUT, bool AF32>
__global__ __launch_bounds__(256) void gemm_big(
    const void* __restrict__ Av, int lda,
    const u16* __restrict__ W, int ldw,
    const float* __restrict__ bias,
    void* __restrict__ outv, int ldo, int K) {
    __shared__ u16 As[128 * 128];
    __shared__ u16 Ws[128 * 128];
    const int tid = threadIdx.x;
    const int w = tid >> 6, lane = tid & 63;
    const int wm = w >> 1, wn = w & 1;
    const int li = lane & 15, lg = lane >> 4;
    const int mB = blockIdx.y * 128, nB = blockIdx.x * 128;
    v4f acc[4][4];
    #pragma unroll
    for (int mt = 0; mt < 4; ++mt)
        #pragma unroll
        for (int nt = 0; nt < 4; ++nt) acc[mt][nt] = (v4f){0.f, 0.f, 0.f, 0.f};
    for (int kc = 0; kc < K; kc += 128) {
        for (int it = 0; it < 8; ++it) {
            int flat = it * 256 + tid;        // 2048 16B-chunks
            int row = flat >> 4, c8 = flat & 15;
            uint4 val;
            if (AF32) {
                const float* Af = (const float*)Av + (size_t)(mB + row) * lda + kc + c8 * 8;
                val = pack8(*(const float4*)Af, *(const float4*)(Af + 4));
            } else {
                val = *(const uint4*)((const u16*)Av + (size_t)(mB + row) * lda + kc + c8 * 8);
            }
            int byte = (row * 256 + c8 * 16) ^ ((row & 7) << 4);
            *(uint4*)((char*)As + byte) = val;
            uint4 wv2 = *(const uint4*)(W + (size_t)(nB + row) * ldw + kc + c8 * 8);
            *(uint4*)((char*)Ws + byte) = wv2;
        }
        __syncthreads();
        for (int ks = 0; ks < 4; ++ks) {
            v8s wf[4];
            #pragma unroll
            for (int nt = 0; nt < 4; ++nt) {
                int row = wn * 64 + nt * 16 + li;
                int byte = (row * 256 + ks * 64 + lg * 16) ^ ((row & 7) << 4);
                wf[nt] = *(const v8s*)((char*)Ws + byte);
            }
            #pragma unroll
            for (int mt = 0; mt < 4; ++mt) {
                int row = wm * 64 + mt * 16 + li;
                int byte = (row * 256 + ks * 64 + lg * 16) ^ ((row & 7) << 4);
                v8s af = *(const v8s*)((char*)As + byte);
                #pragma unroll
                for (int nt = 0; nt < 4; ++nt)
                    acc[mt][nt] = __builtin_amdgcn_mfma_f32_16x16x32_bf16(af, wf[nt], acc[mt][nt], 0, 0, 0);
            }
        }
        __syncthreads();
    }
    #pragma unroll
    for (int mt = 0; mt < 4; ++mt) {
        #pragma unroll
        for (int r = 0; r < 4; ++r) {
            int m = mB + wm * 64 + mt * 16 + lg * 4 + r;
            #pragma unroll
            for (int nt = 0; nt < 4; ++nt) {
                int n = nB + wn * 64 + nt * 16 + li;
                float v = acc[mt][nt][r] + bias[n];
                if (OUT == 0) {
                    ((float*)outv)[(size_t)m * ldo + n] = v;
                } else if (OUT == 1) {
                    ((u16*)outv)[(size_t)m * ldo + n] = f2bf(v);
                } else {
                    int mm = (m & 63) * TDEC_ + (m >> 6);
                    ((float*)outv)[(size_t)mm * ldo + n] = v;
                }
            }
        }
    }
}

// ---------------- LayerNorm+ReLU, bf16 in-place ----------------
__global__ __launch_bounds__(256) void ln_relu_b(u16* __restrict__ x, const float* __restrict__ g,
                                                 const float* __restrict__ bb) {
    int row = blockIdx.x, tid = threadIdx.x;
    u16* xr = x + (size_t)row * 2048;
    __shared__ float red[256];
    uint4 v = *(const uint4*)(xr + tid * 8);
    const u16* pv = (const u16*)&v;
    float lv[8];
    float s = 0.f;
    #pragma unroll
    for (int e = 0; e < 8; ++e) { lv[e] = bf2f(pv[e]); s += lv[e]; }
    red[tid] = s;
    __syncthreads();
    for (int off = 128; off; off >>= 1) {
        if (tid < off) red[tid] += red[tid + off];
        __syncthreads();
    }
    float mu = red[0] * (1.f / 2048.f);
    __syncthreads();
    s = 0.f;
    #pragma unroll
    for (int e = 0; e < 8; ++e) { float d = lv[e] - mu; s += d * d; }
    red[tid] = s;
    __syncthreads();
    for (int off = 128; off; off >>= 1) {
        if (tid < off) red[tid] += red[tid + off];
        __syncthreads();
    }
    float inv = rsqrtf(red[0] * (1.f / 2048.f) + 1e-5f);
    const float4 g1 = *(const float4*)(g + tid * 8), g2 = *(const float4*)(g + tid * 8 + 4);
    const float4 b1 = *(const float4*)(bb + tid * 8), b2 = *(const float4*)(bb + tid * 8 + 4);
    float gv[8] = {g1.x, g1.y, g1.z, g1.w, g2.x, g2.y, g2.z, g2.w};
    float bv[8] = {b1.x, b1.y, b1.z, b1.w, b2.x, b2.y, b2.z, b2.w};
    float4 oa, ob;
    float o[8];
    #pragma unroll
    for (int e = 0; e < 8; ++e) o[e] = fmaxf((lv[e] - mu) * inv * gv[e] + bv[e], 0.f);
    oa = make_float4(o[0], o[1], o[2], o[3]);
    ob = make_float4(o[4], o[5], o[6], o[7]);
    *(uint4*)(xr + tid * 8) = pack8(oa, ob);
}

// ---------------- loss ----------------
__global__ void ce_loss(const float* __restrict__ logits, const int* __restrict__ target,
                        float* __restrict__ acc) {
    const int r = blockIdx.x;   // = b*TDEC + t
    const float* row = logits + (size_t)r * VV;
    const int tid = threadIdx.x;
    __shared__ float red[256];
    float lv[4];
    float m = -1e30f;
    #pragma unroll
    for (int i = 0; i < 4; ++i) { lv[i] = row[tid + i * 256]; m = fmaxf(m, lv[i]); }
    red[tid] = m;
    __syncthreads();
    for (int off = 128; off; off >>= 1) {
        if (tid < off) red[tid] = fmaxf(red[tid], red[tid + off]);
        __syncthreads();
    }
    m = red[0];
    __syncthreads();
    float s = 0.f;
    #pragma unroll
    for (int i = 0; i < 4; ++i) s += expf(lv[i] - m);
    red[tid] = s;
    __syncthreads();
    for (int off = 128; off; off >>= 1) {
        if (tid < off) red[tid] += red[tid + off];
        __syncthreads();
    }
    if (tid == 0) {
        const float nll = logf(red[0]) + m - row[target[r]];
        atomicAdd(acc, nll);
    }
}

__global__ void finalize_loss(const float* __restrict__ acc, float* __restrict__ out) {
    out[0] = acc[0] * (1.f / 4096.f);
}

// ---------------- host ----------------
extern "C" void kernel_launch(void* const* d_in, const int* in_sizes, int n_in,
                              void* d_out, int out_size, void* d_ws, size_t ws_size,
                              hipStream_t stream) {
    const float* enc       = (const float*)d_in[0];
    const int*   target    = (const int*)d_in[1];
    const float* emb_table = (const float*)d_in[2];
    const float* att_wq    = (const float*)d_in[3];
    const float* att_bq    = (const float*)d_in[4];
    const float* att_wk    = (const float*)d_in[5];
    const float* att_bk    = (const float*)d_in[6];
    const float* att_wv    = (const float*)d_in[7];
    const float* att_bv    = (const float*)d_in[8];
    const float* w_ih0     = (const float*)d_in[9];
    const float* w_hh0     = (const float*)d_in[10];
    const float* b_ih0     = (const float*)d_in[11];
    const float* b_hh0     = (const float*)d_in[12];
    const float* w_ih1     = (const float*)d_in[13];
    const float* w_hh1     = (const float*)d_in[14];
    const float* b_ih1     = (const float*)d_in[15];
    const float* b_hh1     = (const float*)d_in[16];
    const float* mlp_w1    = (const float*)d_in[17];
    const float* mlp_b1    = (const float*)d_in[18];
    const float* ln_g      = (const float*)d_in[19];
    const float* ln_b      = (const float*)d_in[20];
    const float* mlp_w2    = (const float*)d_in[21];
    const float* mlp_b2    = (const float*)d_in[22];
    float* out = (float*)d_out;
    char* ws = (char*)d_ws;

    // byte offsets (all 256-aligned)
    size_t off = 0;
    auto alloc = [&](size_t bytes) { size_t o = off; off += (bytes + 255) & ~(size_t)255; return o; };
    u16*   Kb    = (u16*)(ws + alloc((size_t)BQ * TENC_ * AA * 2));
    u16*   Vb    = (u16*)(ws + alloc((size_t)BQ * TENC_ * AA * 2));
    u16*   Eb    = (u16*)(ws + alloc((size_t)TDEC_ * BQ * AA * 2));
    u16*   wcat0 = (u16*)(ws + alloc((size_t)4096 * 2048 * 2));
    u16*   wcat1 = (u16*)(ws + alloc((size_t)4096 * 2048 * 2));
    u16*   wkb   = (u16*)(ws + alloc((size_t)AA * HH * 2));
    u16*   wvb   = (u16*)(ws + alloc((size_t)AA * HH * 2));
    u16*   wqb   = (u16*)(ws + alloc((size_t)AA * HH * 2));
    u16*   w1b   = (u16*)(ws + alloc((size_t)2 * VV * HH * 2));
    u16*   w2b   = (u16*)(ws + alloc((size_t)VV * 2 * VV * 2));
    float* gp    = (float*)(ws + alloc((size_t)4 * 64 * 4096 * 4));
    float* qp    = (float*)(ws + alloc((size_t)2 * 64 * 512 * 4));
    float* sraw  = (float*)(ws + alloc((size_t)BQ * TENC_ * 4));
    u16*   h0b   = (u16*)(ws + alloc((size_t)BQ * HH * 2));
    u16*   h1b   = (u16*)(ws + alloc((size_t)BQ * HH * 2));
    u16*   attnb = (u16*)(ws + alloc((size_t)BQ * AA * 2));
    float* c0    = (float*)(ws + alloc((size_t)BQ * HH * 4));
    float* c1    = (float*)(ws + alloc((size_t)BQ * HH * 4));
    u16*   h1a   = (u16*)(ws + alloc((size_t)TDEC_ * BQ * HH * 2));
    u16*   x1b   = (u16*)(ws + alloc((size_t)TDEC_ * BQ * 2 * VV * 2));
    float* lacc  = (float*)(ws + alloc(256));

    // ---- prologue: weight conversion ----
    build_wcat<<<4096, 256, 0, stream>>>(w_ih0, w_hh0, wcat0);
    build_wcat<<<4096, 256, 0, stream>>>(w_ih1, w_hh1, wcat1);
    conv_f2b<<<256, 256, 0, stream>>>(att_wk, wkb, AA * HH / 8);
    conv_f2b<<<256, 256, 0, stream>>>(att_wv, wvb, AA * HH / 8);
    conv_f2b<<<256, 256, 0, stream>>>(att_wq, wqb, AA * HH / 8);
    conv_f2b<<<1024, 256, 0, stream>>>(mlp_w1, w1b, 2 * VV * HH / 8);
    conv_f2b<<<1024, 256, 0, stream>>>(mlp_w2, w2b, VV * 2 * VV / 8);
    embed_k<<<TDEC_ * BQ, 64, 0, stream>>>(target, emb_table, Eb);

    hipMemsetAsync(h0b, 0, (size_t)BQ * HH * 2, stream);
    hipMemsetAsync(h1b, 0, (size_t)BQ * HH * 2, stream);
    hipMemsetAsync(attnb, 0, (size_t)BQ * AA * 2, stream);
    hipMemsetAsync(c0, 0, (size_t)BQ * HH * 4, stream);
    hipMemsetAsync(c1, 0, (size_t)BQ * HH * 4, stream);
    hipMemsetAsync(lacc, 0, 4, stream);

    // K/V projection over encoder states: [32768, 512] = enc[32768,1024] @ w^T
    gemm_big<1, true><<<dim3(4, 256), 256, 0, stream>>>(enc, HH, wkb, HH, att_bk, Kb, AA, HH);
    gemm_big<1, true><<<dim3(4, 256), 256, 0, stream>>>(enc, HH, wvb, HH, att_bv, Vb, AA, HH);

    // ---- recurrence ----
    for (int t = 0; t < TDEC_; ++t) {
        const u16* et = Eb + (size_t)t * BQ * AA;
        // layer 0: x0 = [e | attn | h0],  W = [w_ih0 | w_hh0]
        gemm_step<<<dim3(64, 4), 256, 0, stream>>>(
            et, attnb, h0b, h0b + 512, AA, AA, HH, HH, wcat0, 2048, gp, 4096);
        cell_k<<<BQ * HH / 256, 256, 0, stream>>>(gp, b_ih0, b_hh0, c0, h0b, nullptr);
        // layer 1: x1 = [h0 | h1],  W = [w_ih1 | w_hh1]
        gemm_step<<<dim3(64, 4), 256, 0, stream>>>(
            h0b, h0b + 512, h1b, h1b + 512, HH, HH, HH, HH, wcat1, 2048, gp, 4096);
        cell_k<<<BQ * HH / 256, 256, 0, stream>>>(gp, b_ih1, b_hh1, c1, h1b, h1a + (size_t)t * BQ * HH);
        // q = h1 @ wq^T (2 K-chunks)
        gemm_step<<<dim3(8, 2), 256, 0, stream>>>(
            h1b, h1b + 512, h1b, h1b, HH, HH, HH, HH, wqb, HH, qp, 512);
        scores_k<<<dim3(64, 8), 256, 0, stream>>>(Kb, qp, att_bq, sraw);
        attnout_k<<<dim3(64, 4), 256, 0, stream>>>(sraw, Vb, attnb);
    }

    // ---- batched MLP head ----
    gemm_big<1, false><<<dim3(16, 32), 256, 0, stream>>>(h1a, HH, w1b, HH, mlp_b1, x1b, 2 * VV, HH);
    ln_relu_b<<<TDEC_ * BQ, 256, 0, stream>>>(x1b, ln_g, ln_b);
    gemm_big<2, false><<<dim3(8, 32), 256, 0, stream>>>(x1b, 2 * VV, w2b, 2 * VV, mlp_b2, out, VV, 2 * VV);

    ce_loss<<<BQ * TDEC_, 256, 0, stream>>>(out, target, lacc);
    finalize_loss<<<1, 1, 0, stream>>>(lacc, out + (size_t)BQ * TDEC_ * VV);
}